// Round 1
// baseline (261.819 us; speedup 1.0000x reference)
//
#include <hip/hip_runtime.h>
#include <math.h>

// EMA along T: y[0]=x[0]; y[t] = (1-a)*y[t-1] + a*x[t], a=0.01.
// Reduce-then-scan over T-chunks; each thread owns 4 channels (float4).

namespace {
constexpr int B = 8;
constexpr int T = 8192;
constexpr int C = 512;
constexpr float ALPHA = 0.01f;
constexpr float DECAY = 1.0f - ALPHA;   // 0.99
constexpr int CHUNK = 128;              // timesteps per block
constexpr int K = T / CHUNK;            // 64 chunks
constexpr int STRIDE4 = C / 4;          // float4 stride per timestep = 128
constexpr int TPB = C / 4;              // 128 threads, 4 channels each
}

__global__ __launch_bounds__(TPB) void ema_ends_kernel(const float* __restrict__ x,
                                                       float* __restrict__ ends) {
    const int k = blockIdx.x;
    const int b = blockIdx.y;
    const int tid = threadIdx.x;
    const float4* xp = reinterpret_cast<const float4*>(x) +
                       (size_t)(b * T + k * CHUNK) * STRIDE4 + tid;
    float4 y;
    if (k == 0) {
        // y_pre = x[0]: uniform recurrence then yields y[0] = 0.99*x0 + 0.01*x0 = x0
        y = xp[0];
    } else {
        y = make_float4(0.f, 0.f, 0.f, 0.f);
    }
#pragma unroll 8
    for (int t = 0; t < CHUNK; ++t) {
        float4 v = xp[(size_t)t * STRIDE4];
        y.x = DECAY * y.x + ALPHA * v.x;
        y.y = DECAY * y.y + ALPHA * v.y;
        y.z = DECAY * y.z + ALPHA * v.z;
        y.w = DECAY * y.w + ALPHA * v.w;
    }
    reinterpret_cast<float4*>(ends)[(size_t)(b * K + k) * STRIDE4 + tid] = y;
}

__global__ __launch_bounds__(TPB) void ema_scan_kernel(const float* __restrict__ x,
                                                       const float* __restrict__ ends,
                                                       float* __restrict__ out,
                                                       float decay_chunk) {
    const int k = blockIdx.x;
    const int b = blockIdx.y;
    const int tid = threadIdx.x;
    const size_t base4 = (size_t)(b * T + k * CHUNK) * STRIDE4 + tid;
    const float4* xp = reinterpret_cast<const float4*>(x) + base4;
    float4* op = reinterpret_cast<float4*>(out) + base4;

    float4 y;
    if (k == 0) {
        y = xp[0];  // y_pre = x[0] trick (see above)
    } else {
        // Carry-in Y_{k-1} = fold of predecessor chunk-end states:
        // Y_m = a^CHUNK * Y_{m-1} + end_m   (ws is 1 MB -> L2-resident reads)
        y = make_float4(0.f, 0.f, 0.f, 0.f);
        const float4* ep = reinterpret_cast<const float4*>(ends) +
                           (size_t)b * K * STRIDE4 + tid;
        for (int m = 0; m < k; ++m) {
            float4 e = ep[(size_t)m * STRIDE4];
            y.x = decay_chunk * y.x + e.x;
            y.y = decay_chunk * y.y + e.y;
            y.z = decay_chunk * y.z + e.z;
            y.w = decay_chunk * y.w + e.w;
        }
    }
#pragma unroll 4
    for (int t = 0; t < CHUNK; ++t) {
        float4 v = xp[(size_t)t * STRIDE4];
        y.x = DECAY * y.x + ALPHA * v.x;
        y.y = DECAY * y.y + ALPHA * v.y;
        y.z = DECAY * y.z + ALPHA * v.z;
        y.w = DECAY * y.w + ALPHA * v.w;
        op[(size_t)t * STRIDE4] = y;
    }
}

// Exact but slow fallback if ws is too small (one block per batch).
__global__ __launch_bounds__(TPB) void ema_seq_kernel(const float* __restrict__ x,
                                                      float* __restrict__ out) {
    const int b = blockIdx.x;
    const int tid = threadIdx.x;
    const float4* xp = reinterpret_cast<const float4*>(x) + (size_t)b * T * STRIDE4 + tid;
    float4* op = reinterpret_cast<float4*>(out) + (size_t)b * T * STRIDE4 + tid;
    float4 y = xp[0];
    for (int t = 0; t < T; ++t) {
        float4 v = xp[(size_t)t * STRIDE4];
        y.x = DECAY * y.x + ALPHA * v.x;
        y.y = DECAY * y.y + ALPHA * v.y;
        y.z = DECAY * y.z + ALPHA * v.z;
        y.w = DECAY * y.w + ALPHA * v.w;
        op[(size_t)t * STRIDE4] = y;
    }
}

extern "C" void kernel_launch(void* const* d_in, const int* in_sizes, int n_in,
                              void* d_out, int out_size, void* d_ws, size_t ws_size,
                              hipStream_t stream) {
    (void)in_sizes; (void)n_in; (void)out_size;
    const float* x = reinterpret_cast<const float*>(d_in[0]);
    float* out = reinterpret_cast<float*>(d_out);

    const size_t ws_need = (size_t)B * K * C * sizeof(float);  // 1 MB
    const float decay_chunk = (float)pow((double)DECAY, (double)CHUNK);

    if (ws_size >= ws_need) {
        float* ends = reinterpret_cast<float*>(d_ws);
        ema_ends_kernel<<<dim3(K, B), dim3(TPB), 0, stream>>>(x, ends);
        ema_scan_kernel<<<dim3(K, B), dim3(TPB), 0, stream>>>(x, ends, out, decay_chunk);
    } else {
        ema_seq_kernel<<<dim3(B), dim3(TPB), 0, stream>>>(x, out);
    }
}